// Round 16
// baseline (76.813 us; speedup 1.0000x reference)
//
#include <hip/hip_runtime.h>
#include <stdint.h>

#define MDIM 4096
#define NDIM 1024
#define KDIM 512
#define TSTEPS 50
#define NCH 16            // 16 chunks of BK=32; all 3 split-products per chunk

typedef _Float16 half8 __attribute__((ext_vector_type(8)));
typedef float    f32x4 __attribute__((ext_vector_type(4)));

typedef const __attribute__((address_space(1))) void cgv_t;
typedef __attribute__((address_space(3))) void lv_t;

__device__ __forceinline__ void gload16(const void* g, void* s) {
    __builtin_amdgcn_global_load_lds((cgv_t*)g, (lv_t*)s, 16, 0, 0);
}

// Pre-kernel (R12's exact proven layout): split fp32 -> (f16, f16 res*2048)
// for A and W^T into 64-row-band chunk images:
//   off = ((r>>6)*16 + c)*4096 + lg*1024 + (((r&63) ^ (lg<<1))<<4)
// (c = chunk of 32 k, lg = 8-k lane group). DMA stages 4KB sub-images
// linearly; frag ds_reads use the same XOR (R12 measured 0 conflicts).
__global__ __launch_bounds__(256) void split_kernel(
    const float* __restrict__ A, const float* __restrict__ W,
    char* __restrict__ A1, char* __restrict__ A2,
    char* __restrict__ B1, char* __restrict__ B2,
    float* __restrict__ tot)
{
    const int blk = blockIdx.x;
    if (blk < 1024) {               // A path: 262144 = 4096 rows x 16 c x 4 lg
        int idx = blk * 256 + threadIdx.x;
        if (idx < MDIM) tot[idx] = 0.0f;    // fused tot-zeroing
        int r = idx >> 6, q = idx & 63, c = q >> 2, lg = q & 3;
        const float* pA = A + (size_t)r * KDIM + c * 32 + lg * 8;
        float4 v0 = *(const float4*)pA;
        float4 v1 = *(const float4*)(pA + 4);
        float v[8] = {v0.x, v0.y, v0.z, v0.w, v1.x, v1.y, v1.z, v1.w};
        half8 h1, h2;
        #pragma unroll
        for (int e = 0; e < 8; ++e) {
            h1[e] = (_Float16)v[e];
            h2[e] = (_Float16)((v[e] - (float)h1[e]) * 2048.0f);
        }
        int off = ((r >> 6) * 16 + c) * 4096 + lg * 1024
                + (((r & 63) ^ (lg << 1)) << 4);
        *(half8*)(A1 + off) = h1;
        *(half8*)(A2 + off) = h2;
    } else {                        // W path: 65536 = 64 (c,lg) x 1024 n
        int idx = (blk - 1024) * 256 + threadIdx.x;
        int q = idx >> 10, n = idx & 1023, c = q >> 2, lg = q & 3;
        float v[8];
        #pragma unroll
        for (int e = 0; e < 8; ++e)
            v[e] = W[(size_t)(c * 32 + lg * 8 + e) * NDIM + n];
        half8 h1, h2;
        #pragma unroll
        for (int e = 0; e < 8; ++e) {
            h1[e] = (_Float16)v[e];
            h2[e] = (_Float16)((v[e] - (float)h1[e]) * 2048.0f);
        }
        int off = ((n >> 6) * 16 + c) * 4096 + lg * 1024
                + (((n & 63) ^ (lg << 1)) << 4);
        *(half8*)(B1 + off) = h1;
        *(half8*)(B2 + off) = h2;
    }
}

// 128x128 tile (halves L2 operand traffic vs R12: 256MB -> 128MB; R15 measured
// the effective frag-read L2 ceiling at ~10.3 TB/s, so traffic is the wall).
// 256 thr = 4 waves in 2x2; wave = 64x64 (4x4 frags of 16x16x32). 2 blocks/CU
// (LDS 2 x 32KB). R12's proven sync: counted vmcnt(8) -> barrier -> 16
// ds_read_b128 + 48 MFMA -> barrier -> stage ch+2. Per-chunk products:
//   acc_hi += a2s*b1 ; acc_hi += a1*b2s ; acc_lo += a1*b1
// Per-element math bit-identical to R12 -> absmax stays 1.0.
__global__ __launch_bounds__(256, 2) void snn_mfma_kernel(
    const char* __restrict__ A1, const char* __restrict__ A2,
    const char* __restrict__ B1, const char* __restrict__ B2,
    const float* __restrict__ bias, float* __restrict__ agg, float* __restrict__ tot)
{
    // per buf: A1[2 bands] | A2 | B1 | B2, each image 8KB (2 x 4KB bands)
    __shared__ __align__(16) unsigned char lds[2][32768];

    const int t  = threadIdx.x;
    const int l  = t & 63;
    const int w  = t >> 6;
    const int li = l & 15;
    const int lg = l >> 4;
    const int qr = (w >> 1) * 64;   // wave quadrant (64x64)
    const int qc = (w & 1) * 64;

    // XCD swizzle (bijective, 256 = 8 x 32): XCD x -> bm in [x*4,x*4+4) x all
    // bn -> per-XCD L2 slice: A 1MB + B 2MB (fits 4MB).
    const int swz = (blockIdx.x & 7) * 32 + (blockIdx.x >> 3);
    const int m0 = (swz >> 3) * 128;
    const int n0 = (swz & 7) * 128;

    // staging: wave w stages image w (A1,A2,B1,B2), 8KB = 8 gload16
    const char* srcw = (w == 0) ? A1 : (w == 1) ? A2 : (w == 2) ? B1 : B2;
    const int band0 = (w < 2) ? (m0 >> 6) : (n0 >> 6);
    const int dstw  = w * 8192;

#define STAGE(buf, ch) do {                                                   \
    _Pragma("unroll") for (int i_ = 0; i_ < 8; ++i_) {                        \
        const int band_ = i_ >> 2, part_ = i_ & 3;                            \
        gload16(srcw + (size_t)(((band0 + band_) * 16 + (ch)) * 4096          \
                                + part_ * 1024 + l * 16),                     \
                &lds[buf][dstw + band_ * 4096 + part_ * 1024]);               \
    }                                                                         \
} while (0)

    // loop-invariant frag byte offsets (within an image, band-resolved)
    const int abase = (w >> 1) * 4096;   // A band for this wave
    const int bbase = (w & 1) * 4096;    // B band
    int aF[4], bF[4];
    #pragma unroll
    for (int i = 0; i < 4; ++i) {
        aF[i] = abase + lg * 1024 + (((i * 16 + li) ^ (lg << 1)) << 4);
        bF[i] = bbase + lg * 1024 + (((i * 16 + li) ^ (lg << 1)) << 4);
    }

    f32x4 acc_lo[4][4], acc_hi[4][4];
    #pragma unroll
    for (int i = 0; i < 4; ++i)
        #pragma unroll
        for (int j = 0; j < 4; ++j) {
            acc_lo[i][j] = (f32x4){0.f, 0.f, 0.f, 0.f};
            acc_hi[i][j] = (f32x4){0.f, 0.f, 0.f, 0.f};
        }

    STAGE(0, 0);
    STAGE(1, 1);

    #pragma unroll 1
    for (int ch = 0; ch < NCH; ++ch) {
        if (ch < NCH - 1) asm volatile("s_waitcnt vmcnt(8)" ::: "memory");
        else              asm volatile("s_waitcnt vmcnt(0)" ::: "memory");
        __builtin_amdgcn_s_barrier();
        asm volatile("" ::: "memory");
        const unsigned char* sb = lds[ch & 1];

        half8 af1[4], af2[4], bf1[4], bf2[4];
        #pragma unroll
        for (int i = 0; i < 4; ++i) {
            af1[i] = *(const half8*)(sb + aF[i]);
            af2[i] = *(const half8*)(sb + 8192 + aF[i]);
            bf1[i] = *(const half8*)(sb + 16384 + bF[i]);
            bf2[i] = *(const half8*)(sb + 24576 + bF[i]);
        }
        #pragma unroll
        for (int i = 0; i < 4; ++i)
            #pragma unroll
            for (int j = 0; j < 4; ++j)
                acc_hi[i][j] = __builtin_amdgcn_mfma_f32_16x16x32_f16(
                    af2[i], bf1[j], acc_hi[i][j], 0, 0, 0);
        #pragma unroll
        for (int i = 0; i < 4; ++i)
            #pragma unroll
            for (int j = 0; j < 4; ++j)
                acc_hi[i][j] = __builtin_amdgcn_mfma_f32_16x16x32_f16(
                    af1[i], bf2[j], acc_hi[i][j], 0, 0, 0);
        #pragma unroll
        for (int i = 0; i < 4; ++i)
            #pragma unroll
            for (int j = 0; j < 4; ++j)
                acc_lo[i][j] = __builtin_amdgcn_mfma_f32_16x16x32_f16(
                    af1[i], bf1[j], acc_lo[i][j], 0, 0, 0);

        __builtin_amdgcn_s_barrier();
        asm volatile("" ::: "memory");
        if (ch + 2 < NCH) STAGE(ch & 1, ch + 2);
    }

    float cb[4];
    #pragma unroll
    for (int j = 0; j < 4; ++j) cb[j] = bias[n0 + qc + j * 16 + li];

    // LIF recurrence: both layers identical -> simulate once.
    // spk_t == reset_{t+1}; fold reset: mem = fma(beta, mem, sp ? c-1 : c)
    #pragma unroll
    for (int i = 0; i < 4; ++i) {
        int rsum[4] = {0, 0, 0, 0};
        #pragma unroll
        for (int j = 0; j < 4; ++j) {
            float c[4], c1[4], mem[4];
            int cnt[4];
            bool sp[4];
            #pragma unroll
            for (int r = 0; r < 4; ++r) {
                c[r]   = fmaf(acc_hi[i][j][r], 4.8828125e-4f, acc_lo[i][j][r])
                       + cb[j];
                c1[r]  = c[r] - 1.0f;
                mem[r] = 0.0f;
                cnt[r] = 0;
                sp[r]  = false;
            }
            #pragma unroll 1
            for (int tt = 0; tt < TSTEPS; ++tt) {
                #pragma unroll
                for (int r = 0; r < 4; ++r) {
                    mem[r] = fmaf(0.95f, mem[r], sp[r] ? c1[r] : c[r]);
                    sp[r]  = mem[r] > 1.0f;
                    cnt[r] += sp[r] ? 1 : 0;
                }
            }
            const int col = n0 + qc + j * 16 + li;
            #pragma unroll
            for (int r = 0; r < 4; ++r) {
                const int row = m0 + qr + i * 16 + lg * 4 + r;
                agg[(size_t)row * NDIM + col] = (float)cnt[r];
                rsum[r] += cnt[r];
            }
        }
        // tot: integer counts, exact in fp32, order-independent atomics
        #pragma unroll
        for (int r = 0; r < 4; ++r) {
            int s = rsum[r];
            s += __shfl_xor(s, 1);
            s += __shfl_xor(s, 2);
            s += __shfl_xor(s, 4);
            s += __shfl_xor(s, 8);
            if (li == 0)
                atomicAdd(&tot[m0 + qr + i * 16 + lg * 4 + r], 2.0f * (float)s);
        }
        __builtin_amdgcn_sched_barrier(0);  // sequence i-blocks: cap liveness
    }
}

extern "C" void kernel_launch(void* const* d_in, const int* in_sizes, int n_in,
                              void* d_out, int out_size, void* d_ws, size_t ws_size,
                              hipStream_t stream) {
    const float* x = (const float*)d_in[0];
    const float* W = (const float*)d_in[1];
    const float* b = (const float*)d_in[2];
    float* agg = (float*)d_out;
    float* tot = agg + (size_t)MDIM * NDIM;

    char* ws = (char*)d_ws;           // needs ws_size >= 10 MB
    char* A1 = ws;                    // 4 MB
    char* A2 = ws + (4 << 20);        // 4 MB
    char* B1 = ws + (8 << 20);        // 1 MB
    char* B2 = ws + (9 << 20);        // 1 MB

    split_kernel<<<1024 + 256, 256, 0, stream>>>(x, W, A1, A2, B1, B2,
                                                 (float*)tot);
    snn_mfma_kernel<<<(MDIM / 128) * (NDIM / 128), 256, 0, stream>>>(
        A1, A2, B1, B2, b, agg, tot);
}

// Round 17
// 53.741 us; speedup vs baseline: 1.4293x; 1.4293x over previous
//
#include <hip/hip_runtime.h>
#include <stdint.h>

#define MDIM 4096
#define NDIM 1024
#define KDIM 512
#define TSTEPS 50
#define NCH 16            // 16 chunks of BK=32; all 3 split-products per chunk

typedef _Float16 half8 __attribute__((ext_vector_type(8)));
typedef float    f32x4 __attribute__((ext_vector_type(4)));

typedef const __attribute__((address_space(1))) void cgv_t;
typedef __attribute__((address_space(3))) void lv_t;

__device__ __forceinline__ void gload16(const void* g, void* s) {
    __builtin_amdgcn_global_load_lds((cgv_t*)g, (lv_t*)s, 16, 0, 0);
}

// Pre-kernel (R12's exact proven layout): split fp32 -> (f16, f16 res*2048)
// for A and W^T into 64-row-band chunk images:
//   off = ((r>>6)*16 + c)*4096 + lg*1024 + (((r&63) ^ (lg<<1))<<4)
__global__ __launch_bounds__(256) void split_kernel(
    const float* __restrict__ A, const float* __restrict__ W,
    char* __restrict__ A1, char* __restrict__ A2,
    char* __restrict__ B1, char* __restrict__ B2,
    float* __restrict__ tot)
{
    const int blk = blockIdx.x;
    if (blk < 1024) {               // A path: 262144 = 4096 rows x 16 c x 4 lg
        int idx = blk * 256 + threadIdx.x;
        if (idx < MDIM) tot[idx] = 0.0f;    // fused tot-zeroing
        int r = idx >> 6, q = idx & 63, c = q >> 2, lg = q & 3;
        const float* pA = A + (size_t)r * KDIM + c * 32 + lg * 8;
        float4 v0 = *(const float4*)pA;
        float4 v1 = *(const float4*)(pA + 4);
        float v[8] = {v0.x, v0.y, v0.z, v0.w, v1.x, v1.y, v1.z, v1.w};
        half8 h1, h2;
        #pragma unroll
        for (int e = 0; e < 8; ++e) {
            h1[e] = (_Float16)v[e];
            h2[e] = (_Float16)((v[e] - (float)h1[e]) * 2048.0f);
        }
        int off = ((r >> 6) * 16 + c) * 4096 + lg * 1024
                + (((r & 63) ^ (lg << 1)) << 4);
        *(half8*)(A1 + off) = h1;
        *(half8*)(A2 + off) = h2;
    } else {                        // W path: 65536 = 64 (c,lg) x 1024 n
        int idx = (blk - 1024) * 256 + threadIdx.x;
        int q = idx >> 10, n = idx & 1023, c = q >> 2, lg = q & 3;
        float v[8];
        #pragma unroll
        for (int e = 0; e < 8; ++e)
            v[e] = W[(size_t)(c * 32 + lg * 8 + e) * NDIM + n];
        half8 h1, h2;
        #pragma unroll
        for (int e = 0; e < 8; ++e) {
            h1[e] = (_Float16)v[e];
            h2[e] = (_Float16)((v[e] - (float)h1[e]) * 2048.0f);
        }
        int off = ((n >> 6) * 16 + c) * 4096 + lg * 1024
                + (((n & 63) ^ (lg << 1)) << 4);
        *(half8*)(B1 + off) = h1;
        *(half8*)(B2 + off) = h2;
    }
}

// 128x64 tile, 512 threads = 8 waves of R12's exact 32x32 wave geometry in a
// 4x2 grid. Grid 512 -> 2 blocks/CU x 8 waves = 16 waves/CU (R12's occupancy)
// with operand traffic 256MB -> 192MB (the measured dominant term).
// Per chunk per wave: 3 gload16 (stage) + 12 ds_read_b128 + 12 MFMA:
//   acc_hi += a2s*b1 ; acc_hi += a1*b2s ; acc_lo += a1*b1
// R12-proven sync: counted vmcnt(3) -> barrier -> compute -> barrier -> stage.
// Per-element math bit-identical to R12 -> absmax stays 1.0.
__global__ __launch_bounds__(512, 4) void snn_mfma_kernel(
    const char* __restrict__ A1, const char* __restrict__ A2,
    const char* __restrict__ B1, const char* __restrict__ B2,
    const float* __restrict__ bias, float* __restrict__ agg, float* __restrict__ tot)
{
    // per buf 24KB: A1 @0 (2 bands x 4KB) | A2 @8192 | B1 @16384 | B2 @20480
    __shared__ __align__(16) unsigned char lds[2][24576];

    const int t  = threadIdx.x;
    const int l  = t & 63;
    const int w  = t >> 6;          // 8 waves
    const int li = l & 15;
    const int lg = l >> 4;
    const int qr = (w >> 1) * 32;   // wave sub-tile origin (4x2 of 32x32)
    const int qc = (w & 1) * 32;

    // XCD swizzle (bijective, 512 = 8 x 64): XCD x -> 4 m-bands (512 rows) x
    // all bn -> per-XCD L2 slice: A 1MB + B 2MB.
    const int swz = (blockIdx.x & 7) * 64 + (blockIdx.x >> 3);
    const int m0 = (swz >> 4) * 128;
    const int n0 = (swz & 15) * 64;

    // staging: 24 1KB strips/chunk, wave w owns strips [3w, 3w+3)
    const char* ssrc[3];
    int sdst[3];
    #pragma unroll
    for (int s_ = 0; s_ < 3; ++s_) {
        const int s = w * 3 + s_;
        const char* img;
        int band, lg_, dst;
        if (s < 16) {               // A strips: 0-7 A1, 8-15 A2
            img  = (s < 8) ? A1 : A2;
            band = (s & 7) >> 2;
            lg_  = s & 3;
            dst  = ((s < 8) ? 0 : 8192) + band * 4096 + lg_ * 1024;
            ssrc[s_] = img + (size_t)(((m0 >> 6) + band) * 16) * 4096
                           + lg_ * 1024 + l * 16;
        } else {                    // B strips: 16-19 B1, 20-23 B2
            img  = (s < 20) ? B1 : B2;
            lg_  = s & 3;
            dst  = ((s < 20) ? 16384 : 20480) + lg_ * 1024;
            ssrc[s_] = img + (size_t)((n0 >> 6) * 16) * 4096
                           + lg_ * 1024 + l * 16;
        }
        sdst[s_] = dst;
    }

#define STAGE(buf, ch) do {                                                   \
    _Pragma("unroll") for (int s_ = 0; s_ < 3; ++s_)                          \
        gload16(ssrc[s_] + (size_t)(ch) * 4096, &lds[buf][sdst[s_]]);         \
} while (0)

    // loop-invariant frag byte offsets
    int aF[2], bF[2];
    #pragma unroll
    for (int i = 0; i < 2; ++i) {
        const int rbase = qr + i * 16;              // 0..112, step 16
        aF[i] = ((rbase >> 6) * 4096) + lg * 1024
              + ((((rbase & 63) + li) ^ (lg << 1)) << 4);
        bF[i] = lg * 1024 + (((qc + i * 16 + li) ^ (lg << 1)) << 4);
    }

    f32x4 acc_lo[2][2], acc_hi[2][2];
    #pragma unroll
    for (int i = 0; i < 2; ++i)
        #pragma unroll
        for (int j = 0; j < 2; ++j) {
            acc_lo[i][j] = (f32x4){0.f, 0.f, 0.f, 0.f};
            acc_hi[i][j] = (f32x4){0.f, 0.f, 0.f, 0.f};
        }

    STAGE(0, 0);
    STAGE(1, 1);

    #pragma unroll 1
    for (int ch = 0; ch < NCH; ++ch) {
        if (ch < NCH - 1) asm volatile("s_waitcnt vmcnt(3)" ::: "memory");
        else              asm volatile("s_waitcnt vmcnt(0)" ::: "memory");
        __builtin_amdgcn_s_barrier();
        asm volatile("" ::: "memory");
        const unsigned char* sb = lds[ch & 1];

        half8 af1[2], af2[2], bf1[2], bf2[2];
        #pragma unroll
        for (int i = 0; i < 2; ++i) {
            af1[i] = *(const half8*)(sb + aF[i]);
            af2[i] = *(const half8*)(sb + 8192 + aF[i]);
            bf1[i] = *(const half8*)(sb + 16384 + bF[i]);
            bf2[i] = *(const half8*)(sb + 20480 + bF[i]);
        }
        #pragma unroll
        for (int i = 0; i < 2; ++i)
            #pragma unroll
            for (int j = 0; j < 2; ++j)
                acc_hi[i][j] = __builtin_amdgcn_mfma_f32_16x16x32_f16(
                    af2[i], bf1[j], acc_hi[i][j], 0, 0, 0);
        #pragma unroll
        for (int i = 0; i < 2; ++i)
            #pragma unroll
            for (int j = 0; j < 2; ++j)
                acc_hi[i][j] = __builtin_amdgcn_mfma_f32_16x16x32_f16(
                    af1[i], bf2[j], acc_hi[i][j], 0, 0, 0);
        #pragma unroll
        for (int i = 0; i < 2; ++i)
            #pragma unroll
            for (int j = 0; j < 2; ++j)
                acc_lo[i][j] = __builtin_amdgcn_mfma_f32_16x16x32_f16(
                    af1[i], bf1[j], acc_lo[i][j], 0, 0, 0);

        __builtin_amdgcn_s_barrier();
        asm volatile("" ::: "memory");
        if (ch + 2 < NCH) STAGE(ch & 1, ch + 2);
    }

    float cb[2];
    #pragma unroll
    for (int j = 0; j < 2; ++j) cb[j] = bias[n0 + qc + j * 16 + li];

    // LIF recurrence: both layers identical -> simulate once.
    // spk_t == reset_{t+1}; fold reset: mem = fma(beta, mem, sp ? c-1 : c)
    #pragma unroll
    for (int i = 0; i < 2; ++i) {
        int rsum[4] = {0, 0, 0, 0};
        #pragma unroll
        for (int j = 0; j < 2; ++j) {
            float c[4], c1[4], mem[4];
            int cnt[4];
            bool sp[4];
            #pragma unroll
            for (int r = 0; r < 4; ++r) {
                c[r]   = fmaf(acc_hi[i][j][r], 4.8828125e-4f, acc_lo[i][j][r])
                       + cb[j];
                c1[r]  = c[r] - 1.0f;
                mem[r] = 0.0f;
                cnt[r] = 0;
                sp[r]  = false;
            }
            #pragma unroll 1
            for (int tt = 0; tt < TSTEPS; ++tt) {
                #pragma unroll
                for (int r = 0; r < 4; ++r) {
                    mem[r] = fmaf(0.95f, mem[r], sp[r] ? c1[r] : c[r]);
                    sp[r]  = mem[r] > 1.0f;
                    cnt[r] += sp[r] ? 1 : 0;
                }
            }
            const int col = n0 + qc + j * 16 + li;
            #pragma unroll
            for (int r = 0; r < 4; ++r) {
                const int row = m0 + qr + i * 16 + lg * 4 + r;
                agg[(size_t)row * NDIM + col] = (float)cnt[r];
                rsum[r] += cnt[r];
            }
        }
        // tot: integer counts, exact in fp32, order-independent atomics
        #pragma unroll
        for (int r = 0; r < 4; ++r) {
            int s = rsum[r];
            s += __shfl_xor(s, 1);
            s += __shfl_xor(s, 2);
            s += __shfl_xor(s, 4);
            s += __shfl_xor(s, 8);
            if (li == 0)
                atomicAdd(&tot[m0 + qr + i * 16 + lg * 4 + r], 2.0f * (float)s);
        }
        __builtin_amdgcn_sched_barrier(0);  // sequence i-blocks: cap liveness
    }
}

extern "C" void kernel_launch(void* const* d_in, const int* in_sizes, int n_in,
                              void* d_out, int out_size, void* d_ws, size_t ws_size,
                              hipStream_t stream) {
    const float* x = (const float*)d_in[0];
    const float* W = (const float*)d_in[1];
    const float* b = (const float*)d_in[2];
    float* agg = (float*)d_out;
    float* tot = agg + (size_t)MDIM * NDIM;

    char* ws = (char*)d_ws;           // needs ws_size >= 10 MB
    char* A1 = ws;                    // 4 MB
    char* A2 = ws + (4 << 20);        // 4 MB
    char* B1 = ws + (8 << 20);        // 1 MB
    char* B2 = ws + (9 << 20);        // 1 MB

    split_kernel<<<1024 + 256, 256, 0, stream>>>(x, W, A1, A2, B1, B2,
                                                 (float*)tot);
    snn_mfma_kernel<<<(MDIM / 128) * (NDIM / 64), 512, 0, stream>>>(
        A1, A2, B1, B2, b, agg, tot);
}

// Round 18
// 53.623 us; speedup vs baseline: 1.4325x; 1.0022x over previous
//
#include <hip/hip_runtime.h>
#include <stdint.h>

#define MDIM 4096
#define NDIM 1024
#define KDIM 512
#define TSTEPS 50
#define NCH 16            // 16 chunks of BK=32; all 3 split-products per chunk

typedef _Float16 half8 __attribute__((ext_vector_type(8)));
typedef float    f32x4 __attribute__((ext_vector_type(4)));

typedef const __attribute__((address_space(1))) void cgv_t;
typedef __attribute__((address_space(3))) void lv_t;

__device__ __forceinline__ void gload16(const void* g, void* s) {
    __builtin_amdgcn_global_load_lds((cgv_t*)g, (lv_t*)s, 16, 0, 0);
}

// Pre-kernel (R12's exact proven layout): split fp32 -> (f16, f16 res*2048)
// for A and W^T into 64-row-band chunk images:
//   off = ((r>>6)*16 + c)*4096 + lg*1024 + (((r&63) ^ (lg<<1))<<4)
__global__ __launch_bounds__(256) void split_kernel(
    const float* __restrict__ A, const float* __restrict__ W,
    char* __restrict__ A1, char* __restrict__ A2,
    char* __restrict__ B1, char* __restrict__ B2,
    float* __restrict__ tot)
{
    const int blk = blockIdx.x;
    if (blk < 1024) {               // A path: 262144 = 4096 rows x 16 c x 4 lg
        int idx = blk * 256 + threadIdx.x;
        if (idx < MDIM) tot[idx] = 0.0f;    // fused tot-zeroing
        int r = idx >> 6, q = idx & 63, c = q >> 2, lg = q & 3;
        const float* pA = A + (size_t)r * KDIM + c * 32 + lg * 8;
        float4 v0 = *(const float4*)pA;
        float4 v1 = *(const float4*)(pA + 4);
        float v[8] = {v0.x, v0.y, v0.z, v0.w, v1.x, v1.y, v1.z, v1.w};
        half8 h1, h2;
        #pragma unroll
        for (int e = 0; e < 8; ++e) {
            h1[e] = (_Float16)v[e];
            h2[e] = (_Float16)((v[e] - (float)h1[e]) * 2048.0f);
        }
        int off = ((r >> 6) * 16 + c) * 4096 + lg * 1024
                + (((r & 63) ^ (lg << 1)) << 4);
        *(half8*)(A1 + off) = h1;
        *(half8*)(A2 + off) = h2;
    } else {                        // W path: 65536 = 64 (c,lg) x 1024 n
        int idx = (blk - 1024) * 256 + threadIdx.x;
        int q = idx >> 10, n = idx & 1023, c = q >> 2, lg = q & 3;
        float v[8];
        #pragma unroll
        for (int e = 0; e < 8; ++e)
            v[e] = W[(size_t)(c * 32 + lg * 8 + e) * NDIM + n];
        half8 h1, h2;
        #pragma unroll
        for (int e = 0; e < 8; ++e) {
            h1[e] = (_Float16)v[e];
            h2[e] = (_Float16)((v[e] - (float)h1[e]) * 2048.0f);
        }
        int off = ((n >> 6) * 16 + c) * 4096 + lg * 1024
                + (((n & 63) ^ (lg << 1)) << 4);
        *(half8*)(B1 + off) = h1;
        *(half8*)(B2 + off) = h2;
    }
}

// 128x64 tile, 512 threads (8 waves, 4x2 of 32x32 sub-tiles), 2 blocks/CU.
// R18: 3 LDS buffers (72KB, still 2 blocks/CU) -> ONE barrier per chunk with
// STAGE issued right after it (overlaps compute); T5 setprio around MFMAs.
// Safety: a wave passes the barrier only after its MFMAs issued => its
// ds_reads are delivered => post-barrier DMA into buf[(ch+2)%3] (last read
// at ch-1) cannot clobber; per-wave vmcnt(3) + barrier covers DMA visibility.
// Per-chunk products: acc_hi += a2s*b1 ; acc_hi += a1*b2s ; acc_lo += a1*b1.
// Per-element math bit-identical to R12/R17 -> absmax stays 1.0.
__global__ __launch_bounds__(512, 4) void snn_mfma_kernel(
    const char* __restrict__ A1, const char* __restrict__ A2,
    const char* __restrict__ B1, const char* __restrict__ B2,
    const float* __restrict__ bias, float* __restrict__ agg, float* __restrict__ tot)
{
    // per buf 24KB: A1 @0 (2 bands x 4KB) | A2 @8192 | B1 @16384 | B2 @20480
    __shared__ __align__(16) unsigned char lds[3][24576];

    const int t  = threadIdx.x;
    const int l  = t & 63;
    const int w  = t >> 6;          // 8 waves
    const int li = l & 15;
    const int lg = l >> 4;
    const int qr = (w >> 1) * 32;   // wave sub-tile origin (4x2 of 32x32)
    const int qc = (w & 1) * 32;

    // XCD swizzle (bijective, 512 = 8 x 64)
    const int swz = (blockIdx.x & 7) * 64 + (blockIdx.x >> 3);
    const int m0 = (swz >> 4) * 128;
    const int n0 = (swz & 15) * 64;

    // staging: 24 1KB strips/chunk, wave w owns strips [3w, 3w+3)
    const char* ssrc[3];
    int sdst[3];
    #pragma unroll
    for (int s_ = 0; s_ < 3; ++s_) {
        const int s = w * 3 + s_;
        const char* img;
        int band, lg_, dst;
        if (s < 16) {               // A strips: 0-7 A1, 8-15 A2
            img  = (s < 8) ? A1 : A2;
            band = (s & 7) >> 2;
            lg_  = s & 3;
            dst  = ((s < 8) ? 0 : 8192) + band * 4096 + lg_ * 1024;
            ssrc[s_] = img + (size_t)(((m0 >> 6) + band) * 16) * 4096
                           + lg_ * 1024 + l * 16;
        } else {                    // B strips: 16-19 B1, 20-23 B2
            img  = (s < 20) ? B1 : B2;
            lg_  = s & 3;
            dst  = ((s < 20) ? 16384 : 20480) + lg_ * 1024;
            ssrc[s_] = img + (size_t)((n0 >> 6) * 16) * 4096
                           + lg_ * 1024 + l * 16;
        }
        sdst[s_] = dst;
    }

#define STAGE(buf, ch) do {                                                   \
    _Pragma("unroll") for (int s_ = 0; s_ < 3; ++s_)                          \
        gload16(ssrc[s_] + (size_t)(ch) * 4096, &lds[buf][sdst[s_]]);         \
} while (0)

    // loop-invariant frag byte offsets
    int aF[2], bF[2];
    #pragma unroll
    for (int i = 0; i < 2; ++i) {
        const int rbase = qr + i * 16;              // 0..112, step 16
        aF[i] = ((rbase >> 6) * 4096) + lg * 1024
              + ((((rbase & 63) + li) ^ (lg << 1)) << 4);
        bF[i] = lg * 1024 + (((qc + i * 16 + li) ^ (lg << 1)) << 4);
    }

    f32x4 acc_lo[2][2], acc_hi[2][2];
    #pragma unroll
    for (int i = 0; i < 2; ++i)
        #pragma unroll
        for (int j = 0; j < 2; ++j) {
            acc_lo[i][j] = (f32x4){0.f, 0.f, 0.f, 0.f};
            acc_hi[i][j] = (f32x4){0.f, 0.f, 0.f, 0.f};
        }

    STAGE(0, 0);
    STAGE(1, 1);

    int bcur = 0, bst = 2;   // compute buffer / stage target (rotate mod 3)

    #pragma unroll 1
    for (int ch = 0; ch < NCH; ++ch) {
        // own chunk-ch loads done (allow the 3 insts of STAGE(ch+1)); barrier
        // then publishes all waves' chunk-ch DMA.
        if (ch < NCH - 1) asm volatile("s_waitcnt vmcnt(3)" ::: "memory");
        else              asm volatile("s_waitcnt vmcnt(0)" ::: "memory");
        __builtin_amdgcn_s_barrier();
        asm volatile("" ::: "memory");
        if (ch + 2 < NCH) STAGE(bst, ch + 2);   // overlaps this chunk's compute

        const unsigned char* sb = lds[bcur];
        half8 af1[2], af2[2], bf1[2], bf2[2];
        #pragma unroll
        for (int i = 0; i < 2; ++i) {
            af1[i] = *(const half8*)(sb + aF[i]);
            af2[i] = *(const half8*)(sb + 8192 + aF[i]);
            bf1[i] = *(const half8*)(sb + 16384 + bF[i]);
            bf2[i] = *(const half8*)(sb + 20480 + bF[i]);
        }
        __builtin_amdgcn_s_setprio(1);
        #pragma unroll
        for (int i = 0; i < 2; ++i)
            #pragma unroll
            for (int j = 0; j < 2; ++j)
                acc_hi[i][j] = __builtin_amdgcn_mfma_f32_16x16x32_f16(
                    af2[i], bf1[j], acc_hi[i][j], 0, 0, 0);
        #pragma unroll
        for (int i = 0; i < 2; ++i)
            #pragma unroll
            for (int j = 0; j < 2; ++j)
                acc_hi[i][j] = __builtin_amdgcn_mfma_f32_16x16x32_f16(
                    af1[i], bf2[j], acc_hi[i][j], 0, 0, 0);
        #pragma unroll
        for (int i = 0; i < 2; ++i)
            #pragma unroll
            for (int j = 0; j < 2; ++j)
                acc_lo[i][j] = __builtin_amdgcn_mfma_f32_16x16x32_f16(
                    af1[i], bf1[j], acc_lo[i][j], 0, 0, 0);
        __builtin_amdgcn_s_setprio(0);

        bcur = (bcur == 2) ? 0 : bcur + 1;
        bst  = (bst  == 2) ? 0 : bst  + 1;
    }

    float cb[2];
    #pragma unroll
    for (int j = 0; j < 2; ++j) cb[j] = bias[n0 + qc + j * 16 + li];

    // LIF recurrence: both layers identical -> simulate once.
    // spk_t == reset_{t+1}; fold reset: mem = fma(beta, mem, sp ? c-1 : c)
    #pragma unroll
    for (int i = 0; i < 2; ++i) {
        int rsum[4] = {0, 0, 0, 0};
        #pragma unroll
        for (int j = 0; j < 2; ++j) {
            float c[4], c1[4], mem[4];
            int cnt[4];
            bool sp[4];
            #pragma unroll
            for (int r = 0; r < 4; ++r) {
                c[r]   = fmaf(acc_hi[i][j][r], 4.8828125e-4f, acc_lo[i][j][r])
                       + cb[j];
                c1[r]  = c[r] - 1.0f;
                mem[r] = 0.0f;
                cnt[r] = 0;
                sp[r]  = false;
            }
            #pragma unroll 1
            for (int tt = 0; tt < TSTEPS; ++tt) {
                #pragma unroll
                for (int r = 0; r < 4; ++r) {
                    mem[r] = fmaf(0.95f, mem[r], sp[r] ? c1[r] : c[r]);
                    sp[r]  = mem[r] > 1.0f;
                    cnt[r] += sp[r] ? 1 : 0;
                }
            }
            const int col = n0 + qc + j * 16 + li;
            #pragma unroll
            for (int r = 0; r < 4; ++r) {
                const int row = m0 + qr + i * 16 + lg * 4 + r;
                agg[(size_t)row * NDIM + col] = (float)cnt[r];
                rsum[r] += cnt[r];
            }
        }
        // tot: integer counts, exact in fp32, order-independent atomics
        #pragma unroll
        for (int r = 0; r < 4; ++r) {
            int s = rsum[r];
            s += __shfl_xor(s, 1);
            s += __shfl_xor(s, 2);
            s += __shfl_xor(s, 4);
            s += __shfl_xor(s, 8);
            if (li == 0)
                atomicAdd(&tot[m0 + qr + i * 16 + lg * 4 + r], 2.0f * (float)s);
        }
        __builtin_amdgcn_sched_barrier(0);  // sequence i-blocks: cap liveness
    }
}

extern "C" void kernel_launch(void* const* d_in, const int* in_sizes, int n_in,
                              void* d_out, int out_size, void* d_ws, size_t ws_size,
                              hipStream_t stream) {
    const float* x = (const float*)d_in[0];
    const float* W = (const float*)d_in[1];
    const float* b = (const float*)d_in[2];
    float* agg = (float*)d_out;
    float* tot = agg + (size_t)MDIM * NDIM;

    char* ws = (char*)d_ws;           // needs ws_size >= 10 MB
    char* A1 = ws;                    // 4 MB
    char* A2 = ws + (4 << 20);        // 4 MB
    char* B1 = ws + (8 << 20);        // 1 MB
    char* B2 = ws + (9 << 20);        // 1 MB

    split_kernel<<<1024 + 256, 256, 0, stream>>>(x, W, A1, A2, B1, B2,
                                                 (float*)tot);
    snn_mfma_kernel<<<(MDIM / 128) * (NDIM / 64), 512, 0, stream>>>(
        A1, A2, B1, B2, b, agg, tot);
}